// Round 7
// baseline (547.797 us; speedup 1.0000x reference)
//
#include <hip/hip_runtime.h>
#include <hip/hip_bf16.h>
#include <math.h>

#define NN 50000
#define NE0 800000
#define ETOT (NE0 + NN)
#define ETOTP (ETOT + NN * 7)        // padded-8 CSR upper bound
#define NG 64
#define SCAN_BLKS ((NN + 63) / 64)   // 782
#define DMAX_THR 8.0f                // defer-max threshold (exp headroom e^8)

typedef __bf16 bf16x8 __attribute__((ext_vector_type(8)));
typedef float  f32x4  __attribute__((ext_vector_type(4)));

__device__ __forceinline__ float bf2f(unsigned short u) {
    return __uint_as_float(((unsigned)u) << 16);
}
__device__ __forceinline__ unsigned short f2bf(float f) {
    unsigned u = __float_as_uint(f);
    return (unsigned short)((u + 0x7FFFu + ((u >> 16) & 1u)) >> 16);  // RNE
}

__device__ __forceinline__ void edge_sd(const int* __restrict__ ei, int e, int& s, int& d) {
    if (e < NE0) { s = ei[e]; d = ei[NE0 + e]; }
    else { s = e - NE0; d = s; }
}

__device__ __forceinline__ float max8(const float* d) {
    return fmaxf(fmaxf(fmaxf(d[0], d[1]), fmaxf(d[2], d[3])),
                 fmaxf(fmaxf(d[4], d[5]), fmaxf(d[6], d[7])));
}
__device__ __forceinline__ float sum8(const float* p) {
    return ((p[0] + p[1]) + (p[2] + p[3])) + ((p[4] + p[5]) + (p[6] + p[7]));
}

// ---------------- CSR build (by dst, rows padded to multiple of 8) ----------------
__global__ __launch_bounds__(256)
void hist_dst(const int* __restrict__ ei, int* __restrict__ deg) {
    int e = blockIdx.x * blockDim.x + threadIdx.x;
    if (e >= ETOT) return;
    int s, d; edge_sd(ei, e, s, d); (void)s;
    atomicAdd(&deg[d], 1);
}

__global__ __launch_bounds__(64)
void scan1(const int* __restrict__ deg, int* __restrict__ psum) {
    int i = blockIdx.x * 64 + threadIdx.x;
    int v = (i < NN) ? ((deg[i] + 7) & ~7) : 0;
#pragma unroll
    for (int off = 1; off < 64; off <<= 1) {
        int t = __shfl_up(v, off);
        if ((int)threadIdx.x >= off) v += t;
    }
    if (threadIdx.x == 63) psum[blockIdx.x] = v;
}

__global__ __launch_bounds__(1024)
void scan2(int* __restrict__ psum) {
    __shared__ int sm[1024];
    int t = threadIdx.x;
    sm[t] = (t < SCAN_BLKS) ? psum[t] : 0;
    __syncthreads();
    for (int off = 1; off < 1024; off <<= 1) {
        int v = (t >= off) ? sm[t - off] : 0;
        __syncthreads();
        sm[t] += v;
        __syncthreads();
    }
    if (t < SCAN_BLKS) psum[t] = (t == 0) ? 0 : sm[t - 1];
}

__global__ __launch_bounds__(64)
void scan3(const int* __restrict__ deg, const int* __restrict__ psum,
           int* __restrict__ rowptr) {
    int i = blockIdx.x * 64 + threadIdx.x;
    int v = (i < NN) ? ((deg[i] + 7) & ~7) : 0;
    int inc = v;
#pragma unroll
    for (int off = 1; off < 64; off <<= 1) {
        int t = __shfl_up(inc, off);
        if ((int)threadIdx.x >= off) inc += t;
    }
    int excl = inc - v + psum[blockIdx.x];
    if (i < NN) rowptr[i] = excl;
    if (i == NN - 1) rowptr[NN] = excl + v;
}

__global__ __launch_bounds__(256)
void scatter_csr(const int* __restrict__ ei, int* __restrict__ cursor,
                 int* __restrict__ col) {
    int e = blockIdx.x * blockDim.x + threadIdx.x;
    if (e >= ETOT) return;
    int s, d; edge_sd(ei, e, s, d);
    int pos = atomicAdd(&cursor[d], 1);
    col[pos] = s;
}

// ---------------- weight pre-pack into MFMA B-fragment layout ----------------
template<int KIN, int NOUT>
__global__ __launch_bounds__(256)
void wfrag_prep(const float* __restrict__ W, unsigned short* __restrict__ Wf) {
    constexpr int KB = KIN / 32;
    int tid = blockIdx.x * 256 + threadIdx.x;
    if (tid >= KIN * NOUT) return;
    int j = tid & 7;
    int l = (tid >> 3) & 63;
    int rest = tid >> 9;
    int kb = rest % KB, t = rest / KB;
    int k = kb * 32 + (l >> 4) * 8 + j;
    int colj = t * 16 + (l & 15);
    Wf[tid] = f2bf(W[(size_t)k * NOUT + colj]);
}

// ---------------- Layer 1 fully fused: raw x gather + on-the-fly lin + GAT ----------------
// 8-edge padded batches, branchless defer-max, x-space accumulation.
__global__ __launch_bounds__(256)
void gat1_fused(const float* __restrict__ x,
                const int* __restrict__ rowptr, const int* __restrict__ deg,
                const int* __restrict__ col,
                const float* __restrict__ W1l, const float* __restrict__ b1l,
                const float* __restrict__ W1r, const float* __restrict__ b1r,
                const float* __restrict__ a1, const float* __restrict__ c1b,
                unsigned short* __restrict__ out) {
    int lane = threadIdx.x & 63;
    int wave0 = (blockIdx.x * blockDim.x + threadIdx.x) >> 6;
    int nwaves = (gridDim.x * blockDim.x) >> 6;
    int ch0 = lane * 4;

    float wl[4][4], wr[4][4];
#pragma unroll
    for (int k = 0; k < 4; ++k) {
        float4 l4 = *reinterpret_cast<const float4*>(W1l + k * 256 + ch0);
        wl[k][0] = l4.x; wl[k][1] = l4.y; wl[k][2] = l4.z; wl[k][3] = l4.w;
        float4 r4 = *reinterpret_cast<const float4*>(W1r + k * 256 + ch0);
        wr[k][0] = r4.x; wr[k][1] = r4.y; wr[k][2] = r4.z; wr[k][3] = r4.w;
    }
    float4 blv = *reinterpret_cast<const float4*>(b1l + ch0);
    float4 brv = *reinterpret_cast<const float4*>(b1r + ch0);
    float4 av  = *reinterpret_cast<const float4*>(a1 + ch0);
    float4 cbv = *reinterpret_cast<const float4*>(c1b + ch0);
    float bl[4] = { blv.x, blv.y, blv.z, blv.w };
    float ar[4] = { av.x, av.y, av.z, av.w };

    const float4* x4 = reinterpret_cast<const float4*>(x);

    for (int node = wave0; node < NN; node += nwaves) {
        float4 xn = x4[node];
        float blr[4];
#pragma unroll
        for (int p = 0; p < 4; ++p) {
            float xr = fmaf(xn.x, wr[0][p], fmaf(xn.y, wr[1][p],
                       fmaf(xn.z, wr[2][p], fmaf(xn.w, wr[3][p],
                       ((const float*)&brv)[p]))));
            blr[p] = bl[p] + xr;
        }
        float m = -INFINITY, l = 0.f;
        float ax = 0.f, ay = 0.f, az = 0.f, aw = 0.f;

        int beg = rowptr[node];
        int npad = rowptr[node + 1] - beg;
        int nreal = deg[node];
        const int* cp = col + beg;
        for (int idx = 0; idx < npad; idx += 8) {
            int cs[8];
#pragma unroll
            for (int q = 0; q < 8; ++q) cs[q] = cp[idx + q];
            float4 v[8];
#pragma unroll
            for (int q = 0; q < 8; ++q) v[q] = x4[cs[q]];
            float dd[8];
#pragma unroll
            for (int q = 0; q < 8; ++q) {
                float d = 0.f;
#pragma unroll
                for (int p = 0; p < 4; ++p) {
                    float u = fmaf(v[q].x, wl[0][p], fmaf(v[q].y, wl[1][p],
                              fmaf(v[q].z, wl[2][p], fmaf(v[q].w, wl[3][p], blr[p]))));
                    u = u > 0.f ? u : 0.2f * u;
                    d = fmaf(u, ar[p], d);
                }
                dd[q] = d;
            }
#pragma unroll
            for (int off = 8; off >= 1; off >>= 1) {
#pragma unroll
                for (int q = 0; q < 8; ++q) dd[q] += __shfl_xor(dd[q], off);
            }
            int nrem = nreal - idx;   // wave-uniform
#pragma unroll
            for (int q = 0; q < 8; ++q) if (q >= nrem) dd[q] = -INFINITY;
            float pmax = max8(dd);
            float nm = (pmax > m + DMAX_THR) ? pmax : m;
            float sc = __expf(m - nm);   // 1.0f on common path
            m = nm;
            float p[8];
#pragma unroll
            for (int q = 0; q < 8; ++q) p[q] = __expf(dd[q] - m);
            l = fmaf(l, sc, sum8(p));
            float sx = (fmaf(p[0], v[0].x, p[1] * v[1].x) + fmaf(p[2], v[2].x, p[3] * v[3].x))
                     + (fmaf(p[4], v[4].x, p[5] * v[5].x) + fmaf(p[6], v[6].x, p[7] * v[7].x));
            float sy = (fmaf(p[0], v[0].y, p[1] * v[1].y) + fmaf(p[2], v[2].y, p[3] * v[3].y))
                     + (fmaf(p[4], v[4].y, p[5] * v[5].y) + fmaf(p[6], v[6].y, p[7] * v[7].y));
            float sz = (fmaf(p[0], v[0].z, p[1] * v[1].z) + fmaf(p[2], v[2].z, p[3] * v[3].z))
                     + (fmaf(p[4], v[4].z, p[5] * v[5].z) + fmaf(p[6], v[6].z, p[7] * v[7].z));
            float sw = (fmaf(p[0], v[0].w, p[1] * v[1].w) + fmaf(p[2], v[2].w, p[3] * v[3].w))
                     + (fmaf(p[4], v[4].w, p[5] * v[5].w) + fmaf(p[6], v[6].w, p[7] * v[7].w));
            ax = fmaf(ax, sc, sx);
            ay = fmaf(ay, sc, sy);
            az = fmaf(az, sc, sz);
            aw = fmaf(aw, sc, sw);
        }
        float inv = 1.f / (l + 1e-16f);
        unsigned short o[4];
#pragma unroll
        for (int p = 0; p < 4; ++p) {
            float v = fmaf(ax, wl[0][p], fmaf(ay, wl[1][p],
                      fmaf(az, wl[2][p], aw * wl[3][p]))) * inv
                      + bl[p] + ((const float*)&cbv)[p];
            o[p] = f2bf(fmaxf(v, 0.f));
        }
        *reinterpret_cast<ushort4*>(out + (size_t)node * 256 + ch0) =
            make_ushort4(o[0], o[1], o[2], o[3]);
    }
}

// ---------------- fused MFMA GEMM ----------------
template<int KIN, int NOUT>
__global__ __launch_bounds__(256)
void gemm_mfma2(const unsigned short* __restrict__ X,
                const unsigned short* __restrict__ WfL, const float* __restrict__ bL,
                unsigned short* __restrict__ outL,
                const unsigned short* __restrict__ WfR, const float* __restrict__ bR,
                unsigned short* __restrict__ outR) {
    constexpr int KB = KIN / 32, NT = NOUT / 16;
    int lane = threadIdx.x & 63;
    int wv = threadIdx.x >> 6;
    int row0 = blockIdx.x * 64 + wv * 16;
    int r16 = lane & 15, kg = lane >> 4;

    int arow = row0 + r16; if (arow >= NN) arow = NN - 1;
    const unsigned short* xrow = X + (size_t)arow * KIN + kg * 8;
    bf16x8 af[KB];
#pragma unroll
    for (int kb = 0; kb < KB; ++kb)
        af[kb] = *reinterpret_cast<const bf16x8*>(xrow + kb * 32);

    const unsigned short* Wf[2] = { WfL, WfR };
    const float* bb[2] = { bL, bR };
    unsigned short* oo[2] = { outL, outR };

#pragma unroll
    for (int w = 0; w < 2; ++w) {
        const bf16x8* wbase = reinterpret_cast<const bf16x8*>(Wf[w]) + lane;
        const float* bw = bb[w];
        unsigned short* ow = oo[w];
#pragma unroll 1
        for (int t = 0; t < NT; ++t) {
            f32x4 acc = {0.f, 0.f, 0.f, 0.f};
            const bf16x8* wp = wbase + (size_t)t * KB * 64;
#pragma unroll
            for (int kb = 0; kb < KB; ++kb)
                acc = __builtin_amdgcn_mfma_f32_16x16x32_bf16(af[kb], wp[kb * 64], acc, 0, 0, 0);
            float bv = bw[t * 16 + r16];
#pragma unroll
            for (int rg = 0; rg < 4; ++rg) {
                int row = row0 + kg * 4 + rg;
                if (row < NN)
                    ow[(size_t)row * NOUT + t * 16 + r16] = f2bf(acc[rg] + bv);
            }
        }
    }
}

// ---------------- GATv2 aggregation (layers 2/3): 8-edge padded, branchless defer-max ----------------
template<int H, int C, bool RELU, bool OUT_BF16>
__global__ __launch_bounds__(256)
void gat_fused(const unsigned short* __restrict__ xl, const unsigned short* __restrict__ xr,
               const int* __restrict__ rowptr, const int* __restrict__ deg,
               const int* __restrict__ col,
               const float* __restrict__ att, const float* __restrict__ bias,
               void* __restrict__ outv) {
    constexpr int HC = H * C;
    constexpr int CPL = HC / 64;     // 2 (L2), 4 (L3)
    constexpr int GRP = C / CPL;     // 32, 64
    int lane = threadIdx.x & 63;
    int wave0 = (blockIdx.x * blockDim.x + threadIdx.x) >> 6;
    int nwaves = (gridDim.x * blockDim.x) >> 6;
    int ch0 = lane * CPL;

    float areg[CPL], breg[CPL];
#pragma unroll
    for (int p = 0; p < CPL; ++p) { areg[p] = att[ch0 + p]; breg[p] = bias[ch0 + p]; }

    for (int node = wave0; node < NN; node += nwaves) {
        float xrv[CPL];
        if constexpr (CPL == 4) {
            ushort4 u = *reinterpret_cast<const ushort4*>(xr + (size_t)node * HC + ch0);
            xrv[0] = bf2f(u.x); xrv[1] = bf2f(u.y); xrv[2] = bf2f(u.z); xrv[3] = bf2f(u.w);
        } else {
            ushort2 u = *reinterpret_cast<const ushort2*>(xr + (size_t)node * HC + ch0);
            xrv[0] = bf2f(u.x); xrv[1] = bf2f(u.y);
        }
        float m = -INFINITY, l = 0.f, acc[CPL];
#pragma unroll
        for (int p = 0; p < CPL; ++p) acc[p] = 0.f;

        int beg = rowptr[node];
        int npad = rowptr[node + 1] - beg;
        int nreal = deg[node];
        const int* cp = col + beg;
        for (int idx = 0; idx < npad; idx += 8) {
            int cs[8];
#pragma unroll
            for (int q = 0; q < 8; ++q) cs[q] = cp[idx + q];
            float a[8][CPL];
#pragma unroll
            for (int q = 0; q < 8; ++q) {
                if constexpr (CPL == 4) {
                    ushort4 u = *reinterpret_cast<const ushort4*>(xl + (size_t)cs[q] * HC + ch0);
                    a[q][0] = bf2f(u.x); a[q][1] = bf2f(u.y); a[q][2] = bf2f(u.z); a[q][3] = bf2f(u.w);
                } else {
                    ushort2 u = *reinterpret_cast<const ushort2*>(xl + (size_t)cs[q] * HC + ch0);
                    a[q][0] = bf2f(u.x); a[q][1] = bf2f(u.y);
                }
            }
            float dd[8];
#pragma unroll
            for (int q = 0; q < 8; ++q) {
                float d = 0.f;
#pragma unroll
                for (int p = 0; p < CPL; ++p) {
                    float v = a[q][p] + xrv[p];
                    v = v > 0.f ? v : 0.2f * v;
                    d = fmaf(v, areg[p], d);
                }
                dd[q] = d;
            }
#pragma unroll
            for (int off = GRP >> 1; off >= 1; off >>= 1) {
#pragma unroll
                for (int q = 0; q < 8; ++q) dd[q] += __shfl_xor(dd[q], off);
            }
            int nrem = nreal - idx;   // wave-uniform
#pragma unroll
            for (int q = 0; q < 8; ++q) if (q >= nrem) dd[q] = -INFINITY;
            float pmax = max8(dd);
            float nm = (pmax > m + DMAX_THR) ? pmax : m;
            float sc = __expf(m - nm);   // 1.0f on common path
            m = nm;
            float p[8];
#pragma unroll
            for (int q = 0; q < 8; ++q) p[q] = __expf(dd[q] - m);
            l = fmaf(l, sc, sum8(p));
#pragma unroll
            for (int pc = 0; pc < CPL; ++pc) {
                float s = (fmaf(p[0], a[0][pc], p[1] * a[1][pc]) + fmaf(p[2], a[2][pc], p[3] * a[3][pc]))
                        + (fmaf(p[4], a[4][pc], p[5] * a[5][pc]) + fmaf(p[6], a[6][pc], p[7] * a[7][pc]));
                acc[pc] = fmaf(acc[pc], sc, s);
            }
        }
        float inv = 1.f / (l + 1e-16f);
        float o[CPL];
#pragma unroll
        for (int p = 0; p < CPL; ++p) {
            float v = acc[p] * inv + breg[p];
            if (RELU) v = fmaxf(v, 0.f);
            o[p] = v;
        }
        if constexpr (OUT_BF16) {
            unsigned short* out = (unsigned short*)outv;
            if constexpr (CPL == 4) {
                *reinterpret_cast<ushort4*>(out + (size_t)node * HC + ch0) =
                    make_ushort4(f2bf(o[0]), f2bf(o[1]), f2bf(o[2]), f2bf(o[3]));
            } else {
                *reinterpret_cast<ushort2*>(out + (size_t)node * HC + ch0) =
                    make_ushort2(f2bf(o[0]), f2bf(o[1]));
            }
        } else {
            float* out = (float*)outv;
            if constexpr (CPL == 4) {
                *reinterpret_cast<float4*>(out + (size_t)node * HC + ch0) =
                    make_float4(o[0], o[1], o[2], o[3]);
            } else {
                *reinterpret_cast<float2*>(out + (size_t)node * HC + ch0) =
                    make_float2(o[0], o[1]);
            }
        }
    }
}

// ---------------- pool + head MLP ----------------
__global__ __launch_bounds__(64)
void graph_bounds(const int* __restrict__ batch, float* __restrict__ cnt) {
    int g = threadIdx.x;
    if (g >= NG) return;
    int lo = 0, hi = NN;
    while (lo < hi) { int mid = (lo + hi) >> 1; if (batch[mid] < g) lo = mid + 1; else hi = mid; }
    int lo2 = lo, hi2 = NN;
    while (lo2 < hi2) { int mid = (lo2 + hi2) >> 1; if (batch[mid] < g + 1) lo2 = mid + 1; else hi2 = mid; }
    cnt[g] = (float)(lo2 - lo);
}

__global__ __launch_bounds__(256)
void pool_sum(const float* __restrict__ h, const int* __restrict__ batch,
              float* pooled) {
    __shared__ int gb[32];
    int c = threadIdx.x;
    int n0 = blockIdx.x * 32;
    int n1 = min(n0 + 32, NN);
    int cnt = n1 - n0;
    if (c < cnt) gb[c] = batch[n0 + c];
    __syncthreads();
    if (gb[0] == gb[cnt - 1]) {
        float acc = 0.f;
#pragma unroll 4
        for (int i = 0; i < cnt; ++i) acc += h[(size_t)(n0 + i) * 256 + c];
        atomicAdd(&pooled[gb[0] * 256 + c], acc);
    } else {
        int cur = gb[0]; float acc = 0.f;
        for (int i = 0; i < cnt; ++i) {
            int g = gb[i];
            if (g != cur) { atomicAdd(&pooled[cur * 256 + c], acc); acc = 0.f; cur = g; }
            acc += h[(size_t)(n0 + i) * 256 + c];
        }
        atomicAdd(&pooled[cur * 256 + c], acc);
    }
}

__global__ __launch_bounds__(256)
void mlp_ln(const float* __restrict__ pooled, const float* __restrict__ cnt,
            const float* __restrict__ We1, const float* __restrict__ be1,
            const float* __restrict__ We2, const float* __restrict__ be2,
            const float* __restrict__ lng, const float* __restrict__ lnb,
            float* __restrict__ out) {
    __shared__ float p[256];
    __shared__ float t[512];
    __shared__ float red[8];
    int g = blockIdx.x, tid = threadIdx.x;
    p[tid] = pooled[g * 256 + tid] / fmaxf(cnt[g], 1.0f);
    __syncthreads();
    for (int jj = tid; jj < 512; jj += 256) {
        float s = be1[jj];
        for (int k = 0; k < 256; ++k) s = fmaf(p[k], We1[(size_t)k * 512 + jj], s);
        t[jj] = fmaxf(s, 0.f);
    }
    __syncthreads();
    float z = be2[tid];
    for (int k = 0; k < 512; ++k) z = fmaf(t[k], We2[(size_t)k * 256 + tid], z);
    float sv = z, sq = z * z;
#pragma unroll
    for (int off = 32; off >= 1; off >>= 1) {
        sv += __shfl_xor(sv, off);
        sq += __shfl_xor(sq, off);
    }
    int wv = tid >> 6;
    if ((tid & 63) == 0) { red[wv] = sv; red[4 + wv] = sq; }
    __syncthreads();
    float tot = red[0] + red[1] + red[2] + red[3];
    float totq = red[4] + red[5] + red[6] + red[7];
    float mu = tot * (1.f / 256.f);
    float var = totq * (1.f / 256.f) - mu * mu;
    float r = rsqrtf(var + 1e-5f);
    out[g * 256 + tid] = (z - mu) * r * lng[tid] + lnb[tid];
}

extern "C" void kernel_launch(void* const* d_in, const int* in_sizes, int n_in,
                              void* d_out, int out_size, void* d_ws, size_t ws_size,
                              hipStream_t stream) {
    const float* x   = (const float*)d_in[0];
    const int*   ei  = (const int*)d_in[1];
    const int*   bat = (const int*)d_in[2];
    const float *W1l = (const float*)d_in[3], *b1l = (const float*)d_in[4];
    const float *W1r = (const float*)d_in[5], *b1r = (const float*)d_in[6];
    const float *a1  = (const float*)d_in[7], *c1b = (const float*)d_in[8];
    const float *W2l = (const float*)d_in[9],  *b2l = (const float*)d_in[10];
    const float *W2r = (const float*)d_in[11], *b2r = (const float*)d_in[12];
    const float *a2  = (const float*)d_in[13], *c2b = (const float*)d_in[14];
    const float *W3l = (const float*)d_in[15], *b3l = (const float*)d_in[16];
    const float *W3r = (const float*)d_in[17], *b3r = (const float*)d_in[18];
    const float *a3  = (const float*)d_in[19], *c3b = (const float*)d_in[20];
    const float *We1 = (const float*)d_in[21], *be1 = (const float*)d_in[22];
    const float *We2 = (const float*)d_in[23], *be2 = (const float*)d_in[24];
    const float *lng = (const float*)d_in[25], *lnb = (const float*)d_in[26];

    char* base = (char*)d_ws;
    size_t off = 0;
    auto nxt = [&](size_t bytes) { char* p = base + off; off = (off + bytes + 255) & ~(size_t)255; return p; };
    unsigned short* Abuf = (unsigned short*)nxt((size_t)NN * 256 * 2);
    unsigned short* Bbuf = (unsigned short*)nxt((size_t)NN * 256 * 2);
    unsigned short* Hb16 = (unsigned short*)nxt((size_t)NN * 256 * 2);
    float* Hb32 = (float*)nxt((size_t)NN * 256 * 4);
    int* deg    = (int*)nxt(NN * 4);
    int* rowptr = (int*)nxt((NN + 1) * 4);
    int* cursor = (int*)nxt(NN * 4);
    int* colv   = (int*)nxt((size_t)ETOTP * 4);
    int* psum   = (int*)nxt(1024 * 4);
    float* POOL = (float*)nxt(NG * 256 * 4);
    float* CNT  = (float*)nxt(NG * 4);
    unsigned short* Wf2l = (unsigned short*)nxt(256 * 128 * 2);
    unsigned short* Wf2r = (unsigned short*)nxt(256 * 128 * 2);
    unsigned short* Wf3l = (unsigned short*)nxt(128 * 256 * 2);
    unsigned short* Wf3r = (unsigned short*)nxt(128 * 256 * 2);

    const int GEMM_BLKS = (NN + 63) / 64;
    const int GAT_BLKS = 3125;   // 12500 waves

    // ---- CSR build (padded-8 rows) ----
    hipMemsetAsync(deg, 0, NN * sizeof(int), stream);
    hipMemsetAsync(colv, 0, (size_t)ETOTP * sizeof(int), stream);
    hist_dst<<<(ETOT + 255) / 256, 256, 0, stream>>>(ei, deg);
    scan1<<<SCAN_BLKS, 64, 0, stream>>>(deg, psum);
    scan2<<<1, 1024, 0, stream>>>(psum);
    scan3<<<SCAN_BLKS, 64, 0, stream>>>(deg, psum, rowptr);
    hipMemcpyAsync(cursor, rowptr, NN * sizeof(int), hipMemcpyDeviceToDevice, stream);
    scatter_csr<<<(ETOT + 255) / 256, 256, 0, stream>>>(ei, cursor, colv);

    // ---- weight pre-pack (layers 2/3) ----
    wfrag_prep<256, 128><<<(256 * 128 + 255) / 256, 256, 0, stream>>>(W2l, Wf2l);
    wfrag_prep<256, 128><<<(256 * 128 + 255) / 256, 256, 0, stream>>>(W2r, Wf2r);
    wfrag_prep<128, 256><<<(128 * 256 + 255) / 256, 256, 0, stream>>>(W3l, Wf3l);
    wfrag_prep<128, 256><<<(128 * 256 + 255) / 256, 256, 0, stream>>>(W3r, Wf3r);

    // ---- Layer 1: fully fused from raw x ----
    gat1_fused<<<GAT_BLKS, 256, 0, stream>>>(x, rowptr, deg, colv, W1l, b1l, W1r, b1r, a1, c1b, Hb16);

    // ---- Layer 2: 256 -> (H=2,C=64) ----
    gemm_mfma2<256, 128><<<GEMM_BLKS, 256, 0, stream>>>(Hb16, Wf2l, b2l, Abuf, Wf2r, b2r, Bbuf);
    gat_fused<2, 64, true, true><<<GAT_BLKS, 256, 0, stream>>>(Abuf, Bbuf, rowptr, deg, colv, a2, c2b, Hb16);

    // ---- Layer 3: 128 -> (H=1,C=256), concat=False ----
    gemm_mfma2<128, 256><<<GEMM_BLKS, 256, 0, stream>>>(Hb16, Wf3l, b3l, Abuf, Wf3r, b3r, Bbuf);
    gat_fused<1, 256, false, false><<<GAT_BLKS, 256, 0, stream>>>(Abuf, Bbuf, rowptr, deg, colv, a3, c3b, Hb32);

    // ---- pool + MLP + LN ----
    hipMemsetAsync(POOL, 0, (size_t)NG * 256 * 4, stream);
    graph_bounds<<<1, 64, 0, stream>>>(bat, CNT);
    pool_sum<<<(NN + 31) / 32, 256, 0, stream>>>(Hb32, bat, POOL);
    mlp_ln<<<NG, 256, 0, stream>>>(POOL, CNT, We1, be1, We2, be2, lng, lnb, (float*)d_out);
}

// Round 8
// 480.501 us; speedup vs baseline: 1.1401x; 1.1401x over previous
//
#include <hip/hip_runtime.h>
#include <hip/hip_bf16.h>
#include <math.h>

#define NN 50000
#define NE0 800000
#define ETOT (NE0 + NN)
#define NG 64
#define SCAN_BLKS ((NN + 63) / 64)   // 782
#define DMAX_THR 8.0f                // defer-max threshold (exp headroom e^8)

typedef __bf16 bf16x8 __attribute__((ext_vector_type(8)));
typedef float  f32x4  __attribute__((ext_vector_type(4)));

__device__ __forceinline__ float bf2f(unsigned short u) {
    return __uint_as_float(((unsigned)u) << 16);
}
__device__ __forceinline__ unsigned short f2bf(float f) {
    unsigned u = __float_as_uint(f);
    return (unsigned short)((u + 0x7FFFu + ((u >> 16) & 1u)) >> 16);  // RNE
}

__device__ __forceinline__ void edge_sd(const int* __restrict__ ei, int e, int& s, int& d) {
    if (e < NE0) { s = ei[e]; d = ei[NE0 + e]; }
    else { s = e - NE0; d = s; }
}

// ---------------- CSR build (by dst) ----------------
__global__ __launch_bounds__(256)
void hist_dst(const int* __restrict__ ei, int* __restrict__ deg) {
    int e = blockIdx.x * blockDim.x + threadIdx.x;
    if (e >= ETOT) return;
    int s, d; edge_sd(ei, e, s, d); (void)s;
    atomicAdd(&deg[d], 1);
}

__global__ __launch_bounds__(64)
void scan1(const int* __restrict__ deg, int* __restrict__ psum) {
    int i = blockIdx.x * 64 + threadIdx.x;
    int v = (i < NN) ? deg[i] : 0;
#pragma unroll
    for (int off = 1; off < 64; off <<= 1) {
        int t = __shfl_up(v, off);
        if ((int)threadIdx.x >= off) v += t;
    }
    if (threadIdx.x == 63) psum[blockIdx.x] = v;
}

__global__ __launch_bounds__(1024)
void scan2(int* __restrict__ psum) {
    __shared__ int sm[1024];
    int t = threadIdx.x;
    sm[t] = (t < SCAN_BLKS) ? psum[t] : 0;
    __syncthreads();
    for (int off = 1; off < 1024; off <<= 1) {
        int v = (t >= off) ? sm[t - off] : 0;
        __syncthreads();
        sm[t] += v;
        __syncthreads();
    }
    if (t < SCAN_BLKS) psum[t] = (t == 0) ? 0 : sm[t - 1];
}

__global__ __launch_bounds__(64)
void scan3(const int* __restrict__ deg, const int* __restrict__ psum,
           int* __restrict__ rowptr) {
    int i = blockIdx.x * 64 + threadIdx.x;
    int v = (i < NN) ? deg[i] : 0;
    int inc = v;
#pragma unroll
    for (int off = 1; off < 64; off <<= 1) {
        int t = __shfl_up(inc, off);
        if ((int)threadIdx.x >= off) inc += t;
    }
    int excl = inc - v + psum[blockIdx.x];
    if (i < NN) rowptr[i] = excl;
    if (i == NN - 1) rowptr[NN] = excl + v;   // == ETOT
}

__global__ __launch_bounds__(256)
void scatter_csr(const int* __restrict__ ei, int* __restrict__ cursor,
                 int* __restrict__ col) {
    int e = blockIdx.x * blockDim.x + threadIdx.x;
    if (e >= ETOT) return;
    int s, d; edge_sd(ei, e, s, d);
    int pos = atomicAdd(&cursor[d], 1);
    col[pos] = s;
}

// ---------------- weight pre-pack into MFMA B-fragment layout ----------------
template<int KIN, int NOUT>
__global__ __launch_bounds__(256)
void wfrag_prep(const float* __restrict__ W, unsigned short* __restrict__ Wf) {
    constexpr int KB = KIN / 32;
    int tid = blockIdx.x * 256 + threadIdx.x;
    if (tid >= KIN * NOUT) return;
    int j = tid & 7;
    int l = (tid >> 3) & 63;
    int rest = tid >> 9;
    int kb = rest % KB, t = rest / KB;
    int k = kb * 32 + (l >> 4) * 8 + j;
    int colj = t * 16 + (l & 15);
    Wf[tid] = f2bf(W[(size_t)k * NOUT + colj]);
}

// ---------------- Layer 1 fully fused: raw x gather + on-the-fly lin + GAT ----------------
// wave-per-node dispatch; 4-edge batched, branchy defer-max, x-space accumulation.
__global__ __launch_bounds__(256)
void gat1_fused(const float* __restrict__ x,
                const int* __restrict__ rowptr, const int* __restrict__ col,
                const float* __restrict__ W1l, const float* __restrict__ b1l,
                const float* __restrict__ W1r, const float* __restrict__ b1r,
                const float* __restrict__ a1, const float* __restrict__ c1b,
                unsigned short* __restrict__ out) {
    int lane = threadIdx.x & 63;
    int node = (blockIdx.x * blockDim.x + threadIdx.x) >> 6;
    if (node >= NN) return;
    int ch0 = lane * 4;

    float wl[4][4], wr[4][4];
#pragma unroll
    for (int k = 0; k < 4; ++k) {
        float4 l4 = *reinterpret_cast<const float4*>(W1l + k * 256 + ch0);
        wl[k][0] = l4.x; wl[k][1] = l4.y; wl[k][2] = l4.z; wl[k][3] = l4.w;
        float4 r4 = *reinterpret_cast<const float4*>(W1r + k * 256 + ch0);
        wr[k][0] = r4.x; wr[k][1] = r4.y; wr[k][2] = r4.z; wr[k][3] = r4.w;
    }
    float4 blv = *reinterpret_cast<const float4*>(b1l + ch0);
    float4 brv = *reinterpret_cast<const float4*>(b1r + ch0);
    float4 av  = *reinterpret_cast<const float4*>(a1 + ch0);
    float4 cbv = *reinterpret_cast<const float4*>(c1b + ch0);
    float bl[4] = { blv.x, blv.y, blv.z, blv.w };
    float ar[4] = { av.x, av.y, av.z, av.w };

    const float4* x4 = reinterpret_cast<const float4*>(x);

    float4 xn = x4[node];
    float blr[4];
#pragma unroll
    for (int p = 0; p < 4; ++p) {
        float xr = fmaf(xn.x, wr[0][p], fmaf(xn.y, wr[1][p],
                   fmaf(xn.z, wr[2][p], fmaf(xn.w, wr[3][p],
                   ((const float*)&brv)[p]))));
        blr[p] = bl[p] + xr;
    }
    float m = -INFINITY, l = 0.f;
    float ax = 0.f, ay = 0.f, az = 0.f, aw = 0.f;

    int beg = rowptr[node], end = rowptr[node + 1];
    int idx = beg;
    for (; idx + 3 < end; idx += 4) {
        float4 v[4];
        float dd[4];
#pragma unroll
        for (int q = 0; q < 4; ++q) v[q] = x4[col[idx + q]];
#pragma unroll
        for (int q = 0; q < 4; ++q) {
            float d = 0.f;
#pragma unroll
            for (int p = 0; p < 4; ++p) {
                float u = fmaf(v[q].x, wl[0][p], fmaf(v[q].y, wl[1][p],
                          fmaf(v[q].z, wl[2][p], fmaf(v[q].w, wl[3][p], blr[p]))));
                u = u > 0.f ? u : 0.2f * u;
                d = fmaf(u, ar[p], d);
            }
            dd[q] = d;
        }
#pragma unroll
        for (int off = 8; off >= 1; off >>= 1) {
#pragma unroll
            for (int q = 0; q < 4; ++q) dd[q] += __shfl_xor(dd[q], off);
        }
        float pmax = fmaxf(fmaxf(dd[0], dd[1]), fmaxf(dd[2], dd[3]));
        if (pmax > m + DMAX_THR) {           // rare path
            float sc = __expf(m - pmax);
            l *= sc; ax *= sc; ay *= sc; az *= sc; aw *= sc;
            m = pmax;
        }
        float p0 = __expf(dd[0] - m), p1 = __expf(dd[1] - m);
        float p2 = __expf(dd[2] - m), p3 = __expf(dd[3] - m);
        l += (p0 + p1) + (p2 + p3);
        ax += fmaf(p0, v[0].x, p1 * v[1].x) + fmaf(p2, v[2].x, p3 * v[3].x);
        ay += fmaf(p0, v[0].y, p1 * v[1].y) + fmaf(p2, v[2].y, p3 * v[3].y);
        az += fmaf(p0, v[0].z, p1 * v[1].z) + fmaf(p2, v[2].z, p3 * v[3].z);
        aw += fmaf(p0, v[0].w, p1 * v[1].w) + fmaf(p2, v[2].w, p3 * v[3].w);
    }
    for (; idx < end; ++idx) {
        float4 v0 = x4[col[idx]];
        float d0 = 0.f;
#pragma unroll
        for (int p = 0; p < 4; ++p) {
            float u0 = fmaf(v0.x, wl[0][p], fmaf(v0.y, wl[1][p],
                       fmaf(v0.z, wl[2][p], fmaf(v0.w, wl[3][p], blr[p]))));
            u0 = u0 > 0.f ? u0 : 0.2f * u0;
            d0 = fmaf(u0, ar[p], d0);
        }
#pragma unroll
        for (int off = 8; off >= 1; off >>= 1) d0 += __shfl_xor(d0, off);
        if (d0 > m + DMAX_THR) {
            float sc = __expf(m - d0);
            l *= sc; ax *= sc; ay *= sc; az *= sc; aw *= sc;
            m = d0;
        }
        float p0 = __expf(d0 - m);
        l += p0;
        ax = fmaf(p0, v0.x, ax);
        ay = fmaf(p0, v0.y, ay);
        az = fmaf(p0, v0.z, az);
        aw = fmaf(p0, v0.w, aw);
    }
    float inv = 1.f / (l + 1e-16f);
    unsigned short o[4];
#pragma unroll
    for (int p = 0; p < 4; ++p) {
        float v = fmaf(ax, wl[0][p], fmaf(ay, wl[1][p],
                  fmaf(az, wl[2][p], aw * wl[3][p]))) * inv
                  + bl[p] + ((const float*)&cbv)[p];
        o[p] = f2bf(fmaxf(v, 0.f));
    }
    *reinterpret_cast<ushort4*>(out + (size_t)node * 256 + ch0) =
        make_ushort4(o[0], o[1], o[2], o[3]);
}

// ---------------- fused MFMA GEMM ----------------
template<int KIN, int NOUT>
__global__ __launch_bounds__(256)
void gemm_mfma2(const unsigned short* __restrict__ X,
                const unsigned short* __restrict__ WfL, const float* __restrict__ bL,
                unsigned short* __restrict__ outL,
                const unsigned short* __restrict__ WfR, const float* __restrict__ bR,
                unsigned short* __restrict__ outR) {
    constexpr int KB = KIN / 32, NT = NOUT / 16;
    int lane = threadIdx.x & 63;
    int wv = threadIdx.x >> 6;
    int row0 = blockIdx.x * 64 + wv * 16;
    int r16 = lane & 15, kg = lane >> 4;

    int arow = row0 + r16; if (arow >= NN) arow = NN - 1;
    const unsigned short* xrow = X + (size_t)arow * KIN + kg * 8;
    bf16x8 af[KB];
#pragma unroll
    for (int kb = 0; kb < KB; ++kb)
        af[kb] = *reinterpret_cast<const bf16x8*>(xrow + kb * 32);

    const unsigned short* Wf[2] = { WfL, WfR };
    const float* bb[2] = { bL, bR };
    unsigned short* oo[2] = { outL, outR };

#pragma unroll
    for (int w = 0; w < 2; ++w) {
        const bf16x8* wbase = reinterpret_cast<const bf16x8*>(Wf[w]) + lane;
        const float* bw = bb[w];
        unsigned short* ow = oo[w];
#pragma unroll 1
        for (int t = 0; t < NT; ++t) {
            f32x4 acc = {0.f, 0.f, 0.f, 0.f};
            const bf16x8* wp = wbase + (size_t)t * KB * 64;
#pragma unroll
            for (int kb = 0; kb < KB; ++kb)
                acc = __builtin_amdgcn_mfma_f32_16x16x32_bf16(af[kb], wp[kb * 64], acc, 0, 0, 0);
            float bv = bw[t * 16 + r16];
#pragma unroll
            for (int rg = 0; rg < 4; ++rg) {
                int row = row0 + kg * 4 + rg;
                if (row < NN)
                    ow[(size_t)row * NOUT + t * 16 + r16] = f2bf(acc[rg] + bv);
            }
        }
    }
}

// ---------------- GATv2 aggregation (layers 2/3): wave-per-node, 4-edge batched, defer-max ----------------
template<int H, int C, bool RELU, bool OUT_BF16>
__global__ __launch_bounds__(256)
void gat_fused(const unsigned short* __restrict__ xl, const unsigned short* __restrict__ xr,
               const int* __restrict__ rowptr, const int* __restrict__ col,
               const float* __restrict__ att, const float* __restrict__ bias,
               void* __restrict__ outv) {
    constexpr int HC = H * C;
    constexpr int CPL = HC / 64;     // 2 (L2), 4 (L3)
    constexpr int GRP = C / CPL;     // 32, 64
    int lane = threadIdx.x & 63;
    int node = (blockIdx.x * blockDim.x + threadIdx.x) >> 6;
    if (node >= NN) return;
    int ch0 = lane * CPL;

    float areg[CPL], breg[CPL];
#pragma unroll
    for (int p = 0; p < CPL; ++p) { areg[p] = att[ch0 + p]; breg[p] = bias[ch0 + p]; }

    float xrv[CPL];
    if constexpr (CPL == 4) {
        ushort4 u = *reinterpret_cast<const ushort4*>(xr + (size_t)node * HC + ch0);
        xrv[0] = bf2f(u.x); xrv[1] = bf2f(u.y); xrv[2] = bf2f(u.z); xrv[3] = bf2f(u.w);
    } else {
        ushort2 u = *reinterpret_cast<const ushort2*>(xr + (size_t)node * HC + ch0);
        xrv[0] = bf2f(u.x); xrv[1] = bf2f(u.y);
    }
    float m = -INFINITY, l = 0.f, acc[CPL];
#pragma unroll
    for (int p = 0; p < CPL; ++p) acc[p] = 0.f;

    int beg = rowptr[node], end = rowptr[node + 1];
    int idx = beg;
    for (; idx + 3 < end; idx += 4) {
        float a[4][CPL];
        float dd[4];
#pragma unroll
        for (int q = 0; q < 4; ++q) {
            int s = col[idx + q];
            if constexpr (CPL == 4) {
                ushort4 u = *reinterpret_cast<const ushort4*>(xl + (size_t)s * HC + ch0);
                a[q][0] = bf2f(u.x); a[q][1] = bf2f(u.y); a[q][2] = bf2f(u.z); a[q][3] = bf2f(u.w);
            } else {
                ushort2 u = *reinterpret_cast<const ushort2*>(xl + (size_t)s * HC + ch0);
                a[q][0] = bf2f(u.x); a[q][1] = bf2f(u.y);
            }
        }
#pragma unroll
        for (int q = 0; q < 4; ++q) {
            float d = 0.f;
#pragma unroll
            for (int p = 0; p < CPL; ++p) {
                float v = a[q][p] + xrv[p];
                v = v > 0.f ? v : 0.2f * v;
                d = fmaf(v, areg[p], d);
            }
            dd[q] = d;
        }
#pragma unroll
        for (int off = GRP >> 1; off >= 1; off >>= 1) {
#pragma unroll
            for (int q = 0; q < 4; ++q) dd[q] += __shfl_xor(dd[q], off);
        }
        float pmax = fmaxf(fmaxf(dd[0], dd[1]), fmaxf(dd[2], dd[3]));
        if (pmax > m + DMAX_THR) {
            float sc = __expf(m - pmax);
            l *= sc;
#pragma unroll
            for (int p = 0; p < CPL; ++p) acc[p] *= sc;
            m = pmax;
        }
        float p0 = __expf(dd[0] - m), p1 = __expf(dd[1] - m);
        float p2 = __expf(dd[2] - m), p3 = __expf(dd[3] - m);
        l += (p0 + p1) + (p2 + p3);
#pragma unroll
        for (int p = 0; p < CPL; ++p)
            acc[p] += fmaf(p0, a[0][p], p1 * a[1][p]) + fmaf(p2, a[2][p], p3 * a[3][p]);
    }
    for (; idx < end; ++idx) {
        int s0 = col[idx];
        float a0[CPL];
        if constexpr (CPL == 4) {
            ushort4 u0 = *reinterpret_cast<const ushort4*>(xl + (size_t)s0 * HC + ch0);
            a0[0] = bf2f(u0.x); a0[1] = bf2f(u0.y); a0[2] = bf2f(u0.z); a0[3] = bf2f(u0.w);
        } else {
            ushort2 u0 = *reinterpret_cast<const ushort2*>(xl + (size_t)s0 * HC + ch0);
            a0[0] = bf2f(u0.x); a0[1] = bf2f(u0.y);
        }
        float d0 = 0.f;
#pragma unroll
        for (int p = 0; p < CPL; ++p) {
            float v0 = a0[p] + xrv[p];
            v0 = v0 > 0.f ? v0 : 0.2f * v0;
            d0 = fmaf(v0, areg[p], d0);
        }
#pragma unroll
        for (int off = GRP >> 1; off >= 1; off >>= 1) d0 += __shfl_xor(d0, off);
        if (d0 > m + DMAX_THR) {
            float sc = __expf(m - d0);
            l *= sc;
#pragma unroll
            for (int p = 0; p < CPL; ++p) acc[p] *= sc;
            m = d0;
        }
        float p0 = __expf(d0 - m);
        l += p0;
#pragma unroll
        for (int p = 0; p < CPL; ++p)
            acc[p] = fmaf(p0, a0[p], acc[p]);
    }
    float inv = 1.f / (l + 1e-16f);
    float o[CPL];
#pragma unroll
    for (int p = 0; p < CPL; ++p) {
        float v = acc[p] * inv + breg[p];
        if (RELU) v = fmaxf(v, 0.f);
        o[p] = v;
    }
    if constexpr (OUT_BF16) {
        unsigned short* out = (unsigned short*)outv;
        if constexpr (CPL == 4) {
            *reinterpret_cast<ushort4*>(out + (size_t)node * HC + ch0) =
                make_ushort4(f2bf(o[0]), f2bf(o[1]), f2bf(o[2]), f2bf(o[3]));
        } else {
            *reinterpret_cast<ushort2*>(out + (size_t)node * HC + ch0) =
                make_ushort2(f2bf(o[0]), f2bf(o[1]));
        }
    } else {
        float* out = (float*)outv;
        if constexpr (CPL == 4) {
            *reinterpret_cast<float4*>(out + (size_t)node * HC + ch0) =
                make_float4(o[0], o[1], o[2], o[3]);
        } else {
            *reinterpret_cast<float2*>(out + (size_t)node * HC + ch0) =
                make_float2(o[0], o[1]);
        }
    }
}

// ---------------- pool + head MLP ----------------
__global__ __launch_bounds__(64)
void graph_bounds(const int* __restrict__ batch, float* __restrict__ cnt) {
    int g = threadIdx.x;
    if (g >= NG) return;
    int lo = 0, hi = NN;
    while (lo < hi) { int mid = (lo + hi) >> 1; if (batch[mid] < g) lo = mid + 1; else hi = mid; }
    int lo2 = lo, hi2 = NN;
    while (lo2 < hi2) { int mid = (lo2 + hi2) >> 1; if (batch[mid] < g + 1) lo2 = mid + 1; else hi2 = mid; }
    cnt[g] = (float)(lo2 - lo);
}

__global__ __launch_bounds__(256)
void pool_sum(const float* __restrict__ h, const int* __restrict__ batch,
              float* pooled) {
    __shared__ int gb[32];
    int c = threadIdx.x;
    int n0 = blockIdx.x * 32;
    int n1 = min(n0 + 32, NN);
    int cnt = n1 - n0;
    if (c < cnt) gb[c] = batch[n0 + c];
    __syncthreads();
    if (gb[0] == gb[cnt - 1]) {
        float acc = 0.f;
#pragma unroll 4
        for (int i = 0; i < cnt; ++i) acc += h[(size_t)(n0 + i) * 256 + c];
        atomicAdd(&pooled[gb[0] * 256 + c], acc);
    } else {
        int cur = gb[0]; float acc = 0.f;
        for (int i = 0; i < cnt; ++i) {
            int g = gb[i];
            if (g != cur) { atomicAdd(&pooled[cur * 256 + c], acc); acc = 0.f; cur = g; }
            acc += h[(size_t)(n0 + i) * 256 + c];
        }
        atomicAdd(&pooled[cur * 256 + c], acc);
    }
}

__global__ __launch_bounds__(256)
void mlp_ln(const float* __restrict__ pooled, const float* __restrict__ cnt,
            const float* __restrict__ We1, const float* __restrict__ be1,
            const float* __restrict__ We2, const float* __restrict__ be2,
            const float* __restrict__ lng, const float* __restrict__ lnb,
            float* __restrict__ out) {
    __shared__ float p[256];
    __shared__ float t[512];
    __shared__ float red[8];
    int g = blockIdx.x, tid = threadIdx.x;
    p[tid] = pooled[g * 256 + tid] / fmaxf(cnt[g], 1.0f);
    __syncthreads();
    for (int jj = tid; jj < 512; jj += 256) {
        float s = be1[jj];
        for (int k = 0; k < 256; ++k) s = fmaf(p[k], We1[(size_t)k * 512 + jj], s);
        t[jj] = fmaxf(s, 0.f);
    }
    __syncthreads();
    float z = be2[tid];
    for (int k = 0; k < 512; ++k) z = fmaf(t[k], We2[(size_t)k * 256 + tid], z);
    float sv = z, sq = z * z;
#pragma unroll
    for (int off = 32; off >= 1; off >>= 1) {
        sv += __shfl_xor(sv, off);
        sq += __shfl_xor(sq, off);
    }
    int wv = tid >> 6;
    if ((tid & 63) == 0) { red[wv] = sv; red[4 + wv] = sq; }
    __syncthreads();
    float tot = red[0] + red[1] + red[2] + red[3];
    float totq = red[4] + red[5] + red[6] + red[7];
    float mu = tot * (1.f / 256.f);
    float var = totq * (1.f / 256.f) - mu * mu;
    float r = rsqrtf(var + 1e-5f);
    out[g * 256 + tid] = (z - mu) * r * lng[tid] + lnb[tid];
}

extern "C" void kernel_launch(void* const* d_in, const int* in_sizes, int n_in,
                              void* d_out, int out_size, void* d_ws, size_t ws_size,
                              hipStream_t stream) {
    const float* x   = (const float*)d_in[0];
    const int*   ei  = (const int*)d_in[1];
    const int*   bat = (const int*)d_in[2];
    const float *W1l = (const float*)d_in[3], *b1l = (const float*)d_in[4];
    const float *W1r = (const float*)d_in[5], *b1r = (const float*)d_in[6];
    const float *a1  = (const float*)d_in[7], *c1b = (const float*)d_in[8];
    const float *W2l = (const float*)d_in[9],  *b2l = (const float*)d_in[10];
    const float *W2r = (const float*)d_in[11], *b2r = (const float*)d_in[12];
    const float *a2  = (const float*)d_in[13], *c2b = (const float*)d_in[14];
    const float *W3l = (const float*)d_in[15], *b3l = (const float*)d_in[16];
    const float *W3r = (const float*)d_in[17], *b3r = (const float*)d_in[18];
    const float *a3  = (const float*)d_in[19], *c3b = (const float*)d_in[20];
    const float *We1 = (const float*)d_in[21], *be1 = (const float*)d_in[22];
    const float *We2 = (const float*)d_in[23], *be2 = (const float*)d_in[24];
    const float *lng = (const float*)d_in[25], *lnb = (const float*)d_in[26];

    char* base = (char*)d_ws;
    size_t off = 0;
    auto nxt = [&](size_t bytes) { char* p = base + off; off = (off + bytes + 255) & ~(size_t)255; return p; };
    unsigned short* Abuf = (unsigned short*)nxt((size_t)NN * 256 * 2);
    unsigned short* Bbuf = (unsigned short*)nxt((size_t)NN * 256 * 2);
    unsigned short* Hb16 = (unsigned short*)nxt((size_t)NN * 256 * 2);
    float* Hb32 = (float*)nxt((size_t)NN * 256 * 4);
    int* deg    = (int*)nxt(NN * 4);
    int* rowptr = (int*)nxt((NN + 1) * 4);
    int* cursor = (int*)nxt(NN * 4);
    int* colv   = (int*)nxt((size_t)ETOT * 4);
    int* psum   = (int*)nxt(1024 * 4);
    float* POOL = (float*)nxt(NG * 256 * 4);
    float* CNT  = (float*)nxt(NG * 4);
    unsigned short* Wf2l = (unsigned short*)nxt(256 * 128 * 2);
    unsigned short* Wf2r = (unsigned short*)nxt(256 * 128 * 2);
    unsigned short* Wf3l = (unsigned short*)nxt(128 * 256 * 2);
    unsigned short* Wf3r = (unsigned short*)nxt(128 * 256 * 2);

    const int GEMM_BLKS = (NN + 63) / 64;
    const int NB_NODE = (NN + 3) / 4;   // wave-per-node, 4 waves/block

    // ---- CSR build ----
    hipMemsetAsync(deg, 0, NN * sizeof(int), stream);
    hist_dst<<<(ETOT + 255) / 256, 256, 0, stream>>>(ei, deg);
    scan1<<<SCAN_BLKS, 64, 0, stream>>>(deg, psum);
    scan2<<<1, 1024, 0, stream>>>(psum);
    scan3<<<SCAN_BLKS, 64, 0, stream>>>(deg, psum, rowptr);
    hipMemcpyAsync(cursor, rowptr, NN * sizeof(int), hipMemcpyDeviceToDevice, stream);
    scatter_csr<<<(ETOT + 255) / 256, 256, 0, stream>>>(ei, cursor, colv);

    // ---- weight pre-pack (layers 2/3) ----
    wfrag_prep<256, 128><<<(256 * 128 + 255) / 256, 256, 0, stream>>>(W2l, Wf2l);
    wfrag_prep<256, 128><<<(256 * 128 + 255) / 256, 256, 0, stream>>>(W2r, Wf2r);
    wfrag_prep<128, 256><<<(128 * 256 + 255) / 256, 256, 0, stream>>>(W3l, Wf3l);
    wfrag_prep<128, 256><<<(128 * 256 + 255) / 256, 256, 0, stream>>>(W3r, Wf3r);

    // ---- Layer 1: fully fused from raw x ----
    gat1_fused<<<NB_NODE, 256, 0, stream>>>(x, rowptr, colv, W1l, b1l, W1r, b1r, a1, c1b, Hb16);

    // ---- Layer 2: 256 -> (H=2,C=64) ----
    gemm_mfma2<256, 128><<<GEMM_BLKS, 256, 0, stream>>>(Hb16, Wf2l, b2l, Abuf, Wf2r, b2r, Bbuf);
    gat_fused<2, 64, true, true><<<NB_NODE, 256, 0, stream>>>(Abuf, Bbuf, rowptr, colv, a2, c2b, Hb16);

    // ---- Layer 3: 128 -> (H=1,C=256), concat=False ----
    gemm_mfma2<128, 256><<<GEMM_BLKS, 256, 0, stream>>>(Hb16, Wf3l, b3l, Abuf, Wf3r, b3r, Bbuf);
    gat_fused<1, 256, false, false><<<NB_NODE, 256, 0, stream>>>(Abuf, Bbuf, rowptr, colv, a3, c3b, Hb32);

    // ---- pool + MLP + LN ----
    hipMemsetAsync(POOL, 0, (size_t)NG * 256 * 4, stream);
    graph_bounds<<<1, 64, 0, stream>>>(bat, CNT);
    pool_sum<<<(NN + 31) / 32, 256, 0, stream>>>(Hb32, bat, POOL);
    mlp_ln<<<NG, 256, 0, stream>>>(POOL, CNT, We1, be1, We2, be2, lng, lnb, (float*)d_out);
}